// Round 6
// baseline (298.187 us; speedup 1.0000x reference)
//
#include <hip/hip_runtime.h>
#include <math.h>

#define B_   2
#define S_   2048
#define HID_ 1024
#define D_   64
#define H_   16
#define ROT_ 32
#define M_   (B_*S_)

typedef __attribute__((ext_vector_type(4))) short  short4v;
typedef __attribute__((ext_vector_type(8))) short  short8;
typedef __attribute__((ext_vector_type(4))) float  floatx4;
typedef __attribute__((ext_vector_type(16))) float floatx16;
typedef __attribute__((ext_vector_type(4))) unsigned int uint4v;

__device__ __forceinline__ unsigned short f2bf(float f) {
  unsigned int x = __builtin_bit_cast(unsigned int, f);
  x += 0x7fffu + ((x >> 16) & 1u);   // RNE; inputs finite
  return (unsigned short)(x >> 16);
}
__device__ __forceinline__ unsigned int cvt_pk_bf16(float lo, float hi) {
  unsigned int r;
  asm("v_cvt_pk_bf16_f32 %0, %1, %2" : "=v"(r) : "v"(lo), "v"(hi));
  return r;
}
// async global->LDS, 16B per lane; lds dest = wave-uniform base + lane*16
__device__ __forceinline__ void gload_lds16(const unsigned short* g, unsigned short* l) {
  __builtin_amdgcn_global_load_lds(
      (const __attribute__((address_space(1))) unsigned int*)g,
      (__attribute__((address_space(3))) unsigned int*)l, 16, 0, 0);
}

// ---------------- cast x (fp32 -> bf16) ----------------
__global__ void cast_bf16(const float* __restrict__ in, unsigned short* __restrict__ out) {
  int i = (blockIdx.x * 256 + threadIdx.x) * 4;
  floatx4 v = *(const floatx4*)(in + i);
  unsigned short o[4];
  o[0] = f2bf(v[0]); o[1] = f2bf(v[1]); o[2] = f2bf(v[2]); o[3] = f2bf(v[3]);
  *(unsigned long long*)(out + i) = *(unsigned long long*)o;
}

// ------------- transpose + cast weights: T[n][k] = bf16(W[k][n]) -------------
__global__ void transW(const float* __restrict__ W0, const float* __restrict__ W1,
                       const float* __restrict__ W2, const float* __restrict__ W3,
                       unsigned short* __restrict__ T0, unsigned short* __restrict__ T1,
                       unsigned short* __restrict__ T2, unsigned short* __restrict__ T3) {
  const float* W; unsigned short* T;
  int z = blockIdx.z;
  if (z == 0)      { W = W0; T = T0; }
  else if (z == 1) { W = W1; T = T1; }
  else if (z == 2) { W = W2; T = T2; }
  else             { W = W3; T = T3; }
  __shared__ float tile[32][33];
  int bx = blockIdx.x * 32, by = blockIdx.y * 32;
  int tx = threadIdx.x, ty = threadIdx.y;
  #pragma unroll
  for (int j = 0; j < 4; j++)
    tile[ty + j*8][tx] = W[(size_t)(by + ty + j*8) * HID_ + bx + tx];
  __syncthreads();
  #pragma unroll
  for (int j = 0; j < 4; j++)
    T[(size_t)(bx + ty + j*8) * HID_ + by + tx] = f2bf(tile[tx][ty + j*8]);
}

// ---------------- GEMM: C[M,N] = A[M,K] @ Bt[N,K]^T (+bias) ----------------
// MODE 0: QKV producer. z=0: Q bf16, rope + scale c1. z=1: K bf16, rope.
//         z=2: V bf16 written TRANSPOSED into Vt[b][h][d][s].
template <int MODE>
__global__ __launch_bounds__(256) void gemm_bt(
    const unsigned short* __restrict__ A,
    const unsigned short* __restrict__ Bt0, const unsigned short* __restrict__ Bt1,
    const unsigned short* __restrict__ Bt2,
    const float* __restrict__ bias0, const float* __restrict__ bias1,
    const float* __restrict__ bias2,
    void* __restrict__ out0, void* __restrict__ out1, void* __restrict__ out2,
    const float* __restrict__ sins, float sc0)
{
  const unsigned short* Bt; const float* bias; void* Out; float sc;
  if (blockIdx.z == 0)      { Bt = Bt0; bias = bias0; Out = out0; sc = sc0; }
  else if (blockIdx.z == 1) { Bt = Bt1; bias = bias1; Out = out1; sc = 1.f; }
  else                      { Bt = Bt2; bias = bias2; Out = out2; sc = 1.f; }
  const int K = HID_, N = HID_;
  int m0 = blockIdx.y * 128, n0 = blockIdx.x * 128;
  __shared__ alignas(16) unsigned short sA[128 * 32];
  __shared__ alignas(16) unsigned short sB[128 * 32];
  int t = threadIdx.x;
  int lane = t & 63, wave = t >> 6;
  int quad = lane >> 4, l16 = lane & 15;
  int wr = wave >> 1, wc = wave & 1;

  int srow = (lane >> 2), scol = (lane & 3) * 8;
  const unsigned short* gA0 = A  + (size_t)(m0 + wave*32 +  0 + srow) * K + scol;
  const unsigned short* gA1 = A  + (size_t)(m0 + wave*32 + 16 + srow) * K + scol;
  const unsigned short* gB0 = Bt + (size_t)(n0 + wave*32 +  0 + srow) * K + scol;
  const unsigned short* gB1 = Bt + (size_t)(n0 + wave*32 + 16 + srow) * K + scol;
  unsigned short* lA0 = sA + (wave*32 +  0) * 32;
  unsigned short* lA1 = sA + (wave*32 + 16) * 32;
  unsigned short* lB0 = sB + (wave*32 +  0) * 32;
  unsigned short* lB1 = sB + (wave*32 + 16) * 32;

  floatx4 acc[4][4];
  #pragma unroll
  for (int i = 0; i < 4; i++)
    #pragma unroll
    for (int j = 0; j < 4; j++)
      acc[i][j] = (floatx4){0.f, 0.f, 0.f, 0.f};

  for (int k0 = 0; k0 < K; k0 += 32) {
    gload_lds16(gA0 + k0, lA0);
    gload_lds16(gA1 + k0, lA1);
    gload_lds16(gB0 + k0, lB0);
    gload_lds16(gB1 + k0, lB1);
    __syncthreads();
    short8 af[4], bf[4];
    #pragma unroll
    for (int i = 0; i < 4; i++) {
      af[i] = *(const short8*)(sA + (wr * 64 + i * 16 + l16) * 32 + quad * 8);
      bf[i] = *(const short8*)(sB + (wc * 64 + i * 16 + l16) * 32 + quad * 8);
    }
    #pragma unroll
    for (int i = 0; i < 4; i++)
      #pragma unroll
      for (int j = 0; j < 4; j++)
        acc[i][j] = __builtin_amdgcn_mfma_f32_16x16x32_bf16(af[i], bf[j], acc[i][j], 0, 0, 0);
    __syncthreads();
  }

  // Epilogue. C/D layout: col = lane&15, row = quad*4 + reg.
  #pragma unroll
  for (int i = 0; i < 4; i++) {
    int mbase = m0 + wr * 64 + i * 16 + quad * 4;
    #pragma unroll
    for (int j = 0; j < 4; j++) {
      int n = n0 + wc * 64 + j * 16 + l16;
      float bv = bias ? bias[n] : 0.f;
      if (MODE == 1) {
        #pragma unroll
        for (int r = 0; r < 4; r++)
          ((float*)Out)[(size_t)(mbase + r) * N + n] = acc[i][j][r] + bv;
      } else if (blockIdx.z == 2) {
        // V: write transposed Vt[((b*16+h)*64+dd)*2048 + s], 4 consecutive s packed
        int bb = mbase >> 11, ss = mbase & 2047;
        int hh = n >> 6, dd = n & 63;
        unsigned short pk[4];
        #pragma unroll
        for (int r = 0; r < 4; r++) pk[r] = f2bf(acc[i][j][r] + bv);
        *(unsigned long long*)((unsigned short*)Out +
            (((size_t)(bb * H_ + hh) * D_ + dd) * S_ + ss)) = *(unsigned long long*)pk;
      } else if (j < 2) {
        // rope columns: head-dim index jh = j*16 + l16 < 32 (wave-uniform branch)
        int jh = j * 16 + l16;
        #pragma unroll
        for (int r = 0; r < 4; r++) {
          int row = mbase + r, bb = row >> 11, ss = row & 2047;
          float sn = sins[((size_t)(bb * 2 + 0) * S_ + ss) * ROT_ + jh];
          float cs = sins[((size_t)(bb * 2 + 1) * S_ + ss) * ROT_ + jh];
          float f = (jh & 1) ? (cs + sn) : (cs - sn);
          ((unsigned short*)Out)[(size_t)row * N + n] = f2bf((acc[i][j][r] + bv) * f * sc);
        }
      } else {
        #pragma unroll
        for (int r = 0; r < 4; r++)
          ((unsigned short*)Out)[(size_t)(mbase + r) * N + n] = f2bf((acc[i][j][r] + bv) * sc);
      }
    }
  }
}

// ---- final projection GEMM: 128(M)x64(N) tile, fp32 out, 512 blocks (2/CU) ----
__global__ __launch_bounds__(256) void gemm_bt64(
    const unsigned short* __restrict__ A, const unsigned short* __restrict__ Bt,
    float* __restrict__ Out)
{
  const int K = HID_, N = HID_;
  int m0 = blockIdx.y * 128, n0 = blockIdx.x * 64;
  __shared__ alignas(16) unsigned short sA[128 * 32];
  __shared__ alignas(16) unsigned short sB[64 * 32];
  int t = threadIdx.x;
  int lane = t & 63, wave = t >> 6;
  int quad = lane >> 4, l16 = lane & 15;
  int wr = wave >> 1, wc = wave & 1;   // per-wave 64(M) x 32(N)

  int srow = lane >> 2, scol = (lane & 3) * 8;
  const unsigned short* gA0 = A  + (size_t)(m0 + wave*32 +  0 + srow) * K + scol;
  const unsigned short* gA1 = A  + (size_t)(m0 + wave*32 + 16 + srow) * K + scol;
  const unsigned short* gB0 = Bt + (size_t)(n0 + wave*16 + srow) * K + scol;
  unsigned short* lA0 = sA + (wave*32 +  0) * 32;
  unsigned short* lA1 = sA + (wave*32 + 16) * 32;
  unsigned short* lB0 = sB + (wave*16) * 32;

  floatx4 acc[4][2];
  #pragma unroll
  for (int i = 0; i < 4; i++)
    #pragma unroll
    for (int j = 0; j < 2; j++)
      acc[i][j] = (floatx4){0.f, 0.f, 0.f, 0.f};

  for (int k0 = 0; k0 < K; k0 += 32) {
    gload_lds16(gA0 + k0, lA0);
    gload_lds16(gA1 + k0, lA1);
    gload_lds16(gB0 + k0, lB0);
    __syncthreads();
    short8 af[4], bf[2];
    #pragma unroll
    for (int i = 0; i < 4; i++)
      af[i] = *(const short8*)(sA + (wr * 64 + i * 16 + l16) * 32 + quad * 8);
    #pragma unroll
    for (int j = 0; j < 2; j++)
      bf[j] = *(const short8*)(sB + (wc * 32 + j * 16 + l16) * 32 + quad * 8);
    #pragma unroll
    for (int i = 0; i < 4; i++)
      #pragma unroll
      for (int j = 0; j < 2; j++)
        acc[i][j] = __builtin_amdgcn_mfma_f32_16x16x32_bf16(af[i], bf[j], acc[i][j], 0, 0, 0);
    __syncthreads();
  }

  #pragma unroll
  for (int i = 0; i < 4; i++) {
    int mbase = m0 + wr * 64 + i * 16 + quad * 4;
    #pragma unroll
    for (int j = 0; j < 2; j++) {
      int n = n0 + wc * 32 + j * 16 + l16;
      #pragma unroll
      for (int r = 0; r < 4; r++)
        Out[(size_t)(mbase + r) * N + n] = acc[i][j][r];
    }
  }
}

// ---------------- flash attention: S^T trick + in-block split-K ----------------
// R5 lesson: vmcnt is ORDER-based; bias loads issued AFTER STAGE made the
// compiler's bias-wait (vmcnt(8)) drain the staging queue -> effective prefetch
// depth was 1 in every round (hence the invariant ~98us). R6: (a) bias refills
// double-buffered and issued at body TOP, BEFORE STAGE (sched_barrier pins
// order); uniform s_waitcnt vmcnt(16) == newest {bias(t), stage(t+1..t+2)}:
// stage(t) complete, TWO stages in flight across the barrier. (b) PV upgraded
// 32x32x8 -> 32x32x16: lanes exchange the partner hl-half of P via
// __shfl_xor(.,32) after cvt_pk packing (A-frag k=8hl+j, same operand
// convention as the verified QK kf/qf); halves PV MFMA issues and V ds_reads
// (b64 -> b128). Same products, same sums -> bit-identical math.
__global__ __launch_bounds__(512, 1) void attn(
    const unsigned short* __restrict__ Q, const unsigned short* __restrict__ Kb,
    const unsigned short* __restrict__ Vt, const float* __restrict__ bias,
    unsigned short* __restrict__ Out)
{
  int b = blockIdx.z, h = blockIdx.y;
  int t = threadIdx.x;
  int lane = t & 63, wave = t >> 6;
  int g = wave >> 2, wg = wave & 3;
  int l32 = lane & 31, hl = lane >> 5;
  int s7 = l32 & 7;
  int q0 = blockIdx.x * 128 + wg * 32;
  const int RS = H_ * D_;
  const int NT = S_ / 128;   // 16 tiles of 64 keys per k-half

  // LDS (shorts), per group 32768: K buf[i] at i*4096, V buf[i] at 16384+i*4096
  __shared__ alignas(16) unsigned short smem[65536];   // 128 KB
  unsigned short* bg = smem + g * 32768;

  const unsigned short* Qbase = Q + ((size_t)(b * S_) * H_ + h) * D_;
  const unsigned short* Kbase = Kb + ((size_t)(b * S_) * H_ + h) * D_;
  const unsigned short* Vbase = Vt + ((size_t)(b * H_) + h) * D_ * S_;

  // Q B-frags (n=q=lane&31, k=d=16s+8hl+j), fixed for whole kernel
  short8 qf[4];
  {
    const unsigned short* qp = Qbase + (size_t)(q0 + l32) * RS + 8 * hl;
    qf[0] = *(const short8*)(qp);
    qf[1] = *(const short8*)(qp + 16);
    qf[2] = *(const short8*)(qp + 32);
    qf[3] = *(const short8*)(qp + 48);
  }

  // staging geometry: group-local thread tg covers 16B chunk d=tg (rows 0..31)
  // and d=256+tg (rows 32..63); 8 chunks per 128B row; source chunk pre-swizzled.
  int tg = t & 255;
  int row0 = tg >> 3;                  // 0..31
  int csw  = (tg & 7) ^ (row0 & 7);    // swizzled source chunk (row&7 same for row0+32)
  const unsigned short* gK0 = Kbase + (size_t)(g*1024 + row0)      * RS + csw * 8;
  const unsigned short* gK1 = Kbase + (size_t)(g*1024 + row0 + 32) * RS + csw * 8;
  const unsigned short* gV0 = Vbase + (size_t)(row0)      * S_ + g*1024 + csw * 8;
  const unsigned short* gV1 = Vbase + (size_t)(row0 + 32) * S_ + g*1024 + csw * 8;

  const float* bp = bias + (size_t)b * S_ * S_ + (size_t)(q0 + l32) * S_ + g * 1024 + 4 * hl;

#define STAGE(bi, tk) do { \
    unsigned short* kb_ = bg + (bi) * 4096; \
    unsigned short* vb_ = bg + 16384 + (bi) * 4096; \
    size_t ko_ = (size_t)(tk) * 64 * RS; int vo_ = (tk) * 64; \
    gload_lds16(gK0 + ko_, kb_ + tg * 8); \
    gload_lds16(gK1 + ko_, kb_ + (256 + tg) * 8); \
    gload_lds16(gV0 + vo_, vb_ + tg * 8); \
    gload_lds16(gV1 + vo_, vb_ + (256 + tg) * 8); \
  } while (0)

  float l_run = 0.f;
  floatx16 o0, o1;
  #pragma unroll
  for (int r = 0; r < 16; r++) { o0[r] = 0.f; o1[r] = 0.f; }

  // prologue VMEM order: STAGE(0) 4, bias(0) 8, STAGE(1) 4, STAGE(2) 4.
  STAGE(0, 0);
  floatx4 b0[4], b1[4], bn0[4], bn1[4];
  #pragma unroll
  for (int rg = 0; rg < 4; rg++) {
    b0[rg] = *(const floatx4*)(bp + 8 * rg);
    b1[rg] = *(const floatx4*)(bp + 32 + 8 * rg);
  }
  STAGE(1, 1);
  STAGE(2, 2);

  #pragma unroll 2
  for (int it = 0; it < NT; ++it) {
    int cur = it & 3;
    // in-order vmcnt: newest 16 = {bias(t) 8, stage(t+1) 4, stage(t+2) 4}
    // -> stage(t) complete, deeper stages + current bias stay in flight.
    asm volatile("s_waitcnt vmcnt(16)" ::: "memory");
    __builtin_amdgcn_s_barrier();

    // bias refills for tile it+1, BEFORE the stage (keeps stage queue deep)
    int itn = ((it + 1) & (NT - 1)) * 64;
    #pragma unroll
    for (int rg = 0; rg < 4; rg++) {
      bn0[rg] = *(const floatx4*)(bp + itn + 8 * rg);
      bn1[rg] = *(const floatx4*)(bp + itn + 32 + 8 * rg);
    }
    __builtin_amdgcn_sched_barrier(0);   // pin: bias issued before STAGE
    if (it < NT - 3) STAGE((it + 3) & 3, it + 3);

    const unsigned short* kbuf = bg + cur * 4096;
    const unsigned short* vbuf = bg + 16384 + cur * 4096;

    #pragma unroll
    for (int cc = 0; cc < 2; cc++) {
      // ---- QK^T: S^T rows k = cc*32 .. cc*32+31 (D[m=k][n=q]) ----
      floatx16 st;
      #pragma unroll
      for (int r = 0; r < 16; r++) st[r] = 0.f;
      __builtin_amdgcn_s_setprio(1);
      #pragma unroll
      for (int ks = 0; ks < 4; ks++) {
        short8 kf = *(const short8*)(kbuf + (cc * 32 + l32) * 64 + (((2 * ks + hl) ^ s7) * 8));
        st = __builtin_amdgcn_mfma_f32_32x32x16_bf16(kf, qf[ks], st, 0, 0, 0);
      }
      __builtin_amdgcn_s_setprio(0);

      // ---- softmax: p = exp2(s)*bias, packed bf16 pairs per own k-block ----
      // st[r]: k = (r&3) + 8*(r>>2) + 4*hl (+32cc). Block m = r>>2.
      const floatx4* bl = cc ? b1 : b0;
      unsigned int pk[8], sw[8];
      #pragma unroll
      for (int m = 0; m < 4; m++) {
        float p0 = __builtin_amdgcn_exp2f(st[m * 4 + 0]);
        float p1 = __builtin_amdgcn_exp2f(st[m * 4 + 1]);
        float p2 = __builtin_amdgcn_exp2f(st[m * 4 + 2]);
        float p3 = __builtin_amdgcn_exp2f(st[m * 4 + 3]);
        l_run += (p0 + p1) + (p2 + p3);
        pk[m * 2 + 0] = cvt_pk_bf16(p0 * bl[m][0], p1 * bl[m][1]);
        pk[m * 2 + 1] = cvt_pk_bf16(p2 * bl[m][2], p3 * bl[m][3]);
      }
      // partner hl-half exchange (q is the same in lanes l and l^32)
      #pragma unroll
      for (int u = 0; u < 8; u++) sw[u] = __shfl_xor(pk[u], 32);

      // ---- PV: O += P@V via 32x32x16 (A k=8hl+j). Per kk (16 k each):
      // hl=0: frag = [own m=2kk | partner m=2kk]; hl=1: [partner m=2kk+1 | own m=2kk+1]
      __builtin_amdgcn_s_setprio(1);
      #pragma unroll
      for (int kk = 0; kk < 2; kk++) {
        uint4v w;
        w[0] = hl ? sw[4 * kk + 2] : pk[4 * kk + 0];
        w[1] = hl ? sw[4 * kk + 3] : pk[4 * kk + 1];
        w[2] = hl ? pk[4 * kk + 2] : sw[4 * kk + 0];
        w[3] = hl ? pk[4 * kk + 3] : sw[4 * kk + 1];
        short8 af = __builtin_bit_cast(short8, w);
        int ch = ((4 * cc + 2 * kk + hl) ^ s7) * 8;
        short8 vf0 = *(const short8*)(vbuf + (l32)      * 64 + ch);
        short8 vf1 = *(const short8*)(vbuf + (32 + l32) * 64 + ch);
        o0 = __builtin_amdgcn_mfma_f32_32x32x16_bf16(af, vf0, o0, 0, 0, 0);
        o1 = __builtin_amdgcn_mfma_f32_32x32x16_bf16(af, vf1, o1, 0, 0, 0);
      }
      __builtin_amdgcn_s_setprio(0);
    }

    // rotate bias double-buffer (renamed away under unroll 2)
    #pragma unroll
    for (int rg = 0; rg < 4; rg++) { b0[rg] = bn0[rg]; b1[rg] = bn1[rg]; }
  }
#undef STAGE

  // full k-half denominator for q-row l32 (partner half-lane has the other half)
  float l2 = l_run + __shfl_xor(l_run, 32);

  // combine the two k-halves through LDS (K/V buffers dead after the loop)
  float* sO = (float*)smem;              // 128 q x 64 d fp32 = 32 KB
  float* sL = (float*)(smem + 16384);    // 128 floats

  __syncthreads();
  if (g == 1) {
    #pragma unroll
    for (int r = 0; r < 16; r++) {
      int ql = (r & 3) + 8 * (r >> 2) + 4 * hl;
      sO[(wg * 32 + ql) * 64 + l32]      = o0[r];
      sO[(wg * 32 + ql) * 64 + 32 + l32] = o1[r];
    }
    if (hl == 0) sL[wg * 32 + l32] = l2;
  }
  __syncthreads();
  if (g == 0) {
    float linv = __builtin_amdgcn_rcpf(l2 + sL[wg * 32 + l32]);
    #pragma unroll
    for (int r = 0; r < 16; r++) {
      int ql = (r & 3) + 8 * (r >> 2) + 4 * hl;
      float sc = __shfl(linv, ql);
      size_t base = ((size_t)(b * S_ + q0 + ql) * H_ + h) * D_;
      float a0 = o0[r] + sO[(wg * 32 + ql) * 64 + l32];
      float a1 = o1[r] + sO[(wg * 32 + ql) * 64 + 32 + l32];
      Out[base + l32]      = f2bf(a0 * sc);
      Out[base + 32 + l32] = f2bf(a1 * sc);
    }
  }
}

// ---------------- launch ----------------
extern "C" void kernel_launch(void* const* d_in, const int* in_sizes, int n_in,
                              void* d_out, int out_size, void* d_ws, size_t ws_size,
                              hipStream_t stream) {
  (void)in_sizes; (void)n_in; (void)out_size; (void)ws_size;
  const float* x    = (const float*)d_in[0];
  const float* sins = (const float*)d_in[1];
  const float* ab   = (const float*)d_in[2];
  const float* Wq   = (const float*)d_in[3];
  const float* bq   = (const float*)d_in[4];
  const float* Wk   = (const float*)d_in[5];
  const float* bk   = (const float*)d_in[6];
  const float* Wv   = (const float*)d_in[7];
  const float* bv   = (const float*)d_in[8];
  const float* Wo   = (const float*)d_in[9];
  float* out = (float*)d_out;
  char* ws = (char*)d_ws;

  unsigned short* xb  = (unsigned short*)(ws);                       // 8 MB
  unsigned short* Wqt = (unsigned short*)(ws + ((size_t) 8 << 20));  // 2 MB each
  unsigned short* Wkt = (unsigned short*)(ws + ((size_t)10 << 20));
  unsigned short* Wvt = (unsigned short*)(ws + ((size_t)12 << 20));
  unsigned short* Wot = (unsigned short*)(ws + ((size_t)14 << 20));
  unsigned short* Qb  = (unsigned short*)(ws + ((size_t)16 << 20));  // 8 MB
  unsigned short* Kb  = (unsigned short*)(ws + ((size_t)24 << 20));  // 8 MB
  unsigned short* Vtb = (unsigned short*)(ws + ((size_t)32 << 20));  // 8 MB, [b][h][d][s]
  unsigned short* Ab  = (unsigned short*)(ws + ((size_t)40 << 20));  // 8 MB

  const float c1 = 0.125f * 1.44269504088896f;  // 1/sqrt(D) * log2(e), folded into Q

  cast_bf16<<<dim3((M_ * HID_) / (256 * 4)), dim3(256), 0, stream>>>(x, xb);
  transW<<<dim3(32, 32, 4), dim3(32, 8), 0, stream>>>(Wq, Wk, Wv, Wo, Wqt, Wkt, Wvt, Wot);
  gemm_bt<0><<<dim3(8, 32, 3), dim3(256), 0, stream>>>(xb, Wqt, Wkt, Wvt, bq, bk, bv,
                                                       Qb, Kb, Vtb, sins, c1);
  attn<<<dim3(S_ / 128, H_, B_), dim3(512), 0, stream>>>(Qb, Kb, Vtb, ab, Ab);
  gemm_bt64<<<dim3(HID_ / 64, M_ / 128), dim3(256), 0, stream>>>(Ab, Wot, out);
}

// Round 7
// 261.932 us; speedup vs baseline: 1.1384x; 1.1384x over previous
//
#include <hip/hip_runtime.h>
#include <math.h>

#define B_   2
#define S_   2048
#define HID_ 1024
#define D_   64
#define H_   16
#define ROT_ 32
#define M_   (B_*S_)

typedef __attribute__((ext_vector_type(4))) short  short4v;
typedef __attribute__((ext_vector_type(8))) short  short8;
typedef __attribute__((ext_vector_type(4))) float  floatx4;
typedef __attribute__((ext_vector_type(16))) float floatx16;
typedef __attribute__((ext_vector_type(2))) unsigned int uint2v;

__device__ __forceinline__ unsigned short f2bf(float f) {
  unsigned int x = __builtin_bit_cast(unsigned int, f);
  x += 0x7fffu + ((x >> 16) & 1u);   // RNE; inputs finite
  return (unsigned short)(x >> 16);
}
__device__ __forceinline__ unsigned int cvt_pk_bf16(float lo, float hi) {
  unsigned int r;
  asm("v_cvt_pk_bf16_f32 %0, %1, %2" : "=v"(r) : "v"(lo), "v"(hi));
  return r;
}
// async global->LDS, 16B per lane; lds dest = wave-uniform base + lane*16
__device__ __forceinline__ void gload_lds16(const unsigned short* g, unsigned short* l) {
  __builtin_amdgcn_global_load_lds(
      (const __attribute__((address_space(1))) unsigned int*)g,
      (__attribute__((address_space(3))) unsigned int*)l, 16, 0, 0);
}

// ---------------- cast x (fp32 -> bf16) ----------------
__global__ void cast_bf16(const float* __restrict__ in, unsigned short* __restrict__ out) {
  int i = (blockIdx.x * 256 + threadIdx.x) * 4;
  floatx4 v = *(const floatx4*)(in + i);
  unsigned short o[4];
  o[0] = f2bf(v[0]); o[1] = f2bf(v[1]); o[2] = f2bf(v[2]); o[3] = f2bf(v[3]);
  *(unsigned long long*)(out + i) = *(unsigned long long*)o;
}

// ------------- transpose + cast weights: T[n][k] = bf16(W[k][n]) -------------
__global__ void transW(const float* __restrict__ W0, const float* __restrict__ W1,
                       const float* __restrict__ W2, const float* __restrict__ W3,
                       unsigned short* __restrict__ T0, unsigned short* __restrict__ T1,
                       unsigned short* __restrict__ T2, unsigned short* __restrict__ T3) {
  const float* W; unsigned short* T;
  int z = blockIdx.z;
  if (z == 0)      { W = W0; T = T0; }
  else if (z == 1) { W = W1; T = T1; }
  else if (z == 2) { W = W2; T = T2; }
  else             { W = W3; T = T3; }
  __shared__ float tile[32][33];
  int bx = blockIdx.x * 32, by = blockIdx.y * 32;
  int tx = threadIdx.x, ty = threadIdx.y;
  #pragma unroll
  for (int j = 0; j < 4; j++)
    tile[ty + j*8][tx] = W[(size_t)(by + ty + j*8) * HID_ + bx + tx];
  __syncthreads();
  #pragma unroll
  for (int j = 0; j < 4; j++)
    T[(size_t)(bx + ty + j*8) * HID_ + by + tx] = f2bf(tile[tx][ty + j*8]);
}

// ---------------- GEMM: C[M,N] = A[M,K] @ Bt[N,K]^T (+bias) ----------------
// R7: minimum-2-phase pipeline (catalog T3-lite): double-buffered LDS, STAGE
// of tile t+1 issued BEFORE compute(t), ONE __syncthreads per K-step (its
// implicit vmcnt(0) lands after ~300cyc of ds_read+MFMA instead of after 0).
// Old structure drained the just-issued loads at the barrier (depth 0).
// MODE 0: QKV producer. z=0: Q bf16, rope + scale c1. z=1: K bf16, rope.
//         z=2: V bf16 written TRANSPOSED into Vt[b][h][d][s].
template <int MODE>
__global__ __launch_bounds__(256) void gemm_bt(
    const unsigned short* __restrict__ A,
    const unsigned short* __restrict__ Bt0, const unsigned short* __restrict__ Bt1,
    const unsigned short* __restrict__ Bt2,
    const float* __restrict__ bias0, const float* __restrict__ bias1,
    const float* __restrict__ bias2,
    void* __restrict__ out0, void* __restrict__ out1, void* __restrict__ out2,
    const float* __restrict__ sins, float sc0)
{
  const unsigned short* Bt; const float* bias; void* Out; float sc;
  if (blockIdx.z == 0)      { Bt = Bt0; bias = bias0; Out = out0; sc = sc0; }
  else if (blockIdx.z == 1) { Bt = Bt1; bias = bias1; Out = out1; sc = 1.f; }
  else                      { Bt = Bt2; bias = bias2; Out = out2; sc = 1.f; }
  const int K = HID_, N = HID_;
  int m0 = blockIdx.y * 128, n0 = blockIdx.x * 128;
  __shared__ alignas(16) unsigned short sA[2][128 * 32];   // 16 KB x2
  __shared__ alignas(16) unsigned short sB[2][128 * 32];
  int t = threadIdx.x;
  int lane = t & 63, wave = t >> 6;
  int quad = lane >> 4, l16 = lane & 15;
  int wr = wave >> 1, wc = wave & 1;

  int srow = (lane >> 2), scol = (lane & 3) * 8;
  const unsigned short* gA0 = A  + (size_t)(m0 + wave*32 +  0 + srow) * K + scol;
  const unsigned short* gA1 = A  + (size_t)(m0 + wave*32 + 16 + srow) * K + scol;
  const unsigned short* gB0 = Bt + (size_t)(n0 + wave*32 +  0 + srow) * K + scol;
  const unsigned short* gB1 = Bt + (size_t)(n0 + wave*32 + 16 + srow) * K + scol;

#define GSTAGE(bi, k0) do { \
    gload_lds16(gA0 + (k0), sA[bi] + (wave*32 +  0) * 32); \
    gload_lds16(gA1 + (k0), sA[bi] + (wave*32 + 16) * 32); \
    gload_lds16(gB0 + (k0), sB[bi] + (wave*32 +  0) * 32); \
    gload_lds16(gB1 + (k0), sB[bi] + (wave*32 + 16) * 32); \
  } while (0)

  floatx4 acc[4][4];
  #pragma unroll
  for (int i = 0; i < 4; i++)
    #pragma unroll
    for (int j = 0; j < 4; j++)
      acc[i][j] = (floatx4){0.f, 0.f, 0.f, 0.f};

  GSTAGE(0, 0);
  __syncthreads();                       // buf0 landed
  for (int ks = 0; ks < K / 32; ks++) {
    int cur = ks & 1;
    if (ks + 1 < K / 32) GSTAGE(cur ^ 1, (ks + 1) * 32);   // prefetch in flight
    short8 af[4], bf[4];
    #pragma unroll
    for (int i = 0; i < 4; i++) {
      af[i] = *(const short8*)(sA[cur] + (wr * 64 + i * 16 + l16) * 32 + quad * 8);
      bf[i] = *(const short8*)(sB[cur] + (wc * 64 + i * 16 + l16) * 32 + quad * 8);
    }
    #pragma unroll
    for (int i = 0; i < 4; i++)
      #pragma unroll
      for (int j = 0; j < 4; j++)
        acc[i][j] = __builtin_amdgcn_mfma_f32_16x16x32_bf16(af[i], bf[j], acc[i][j], 0, 0, 0);
    __syncthreads();                     // drains prefetch; readers of buf cur done
  }
#undef GSTAGE

  // Epilogue. C/D layout: col = lane&15, row = quad*4 + reg.
  #pragma unroll
  for (int i = 0; i < 4; i++) {
    int mbase = m0 + wr * 64 + i * 16 + quad * 4;
    #pragma unroll
    for (int j = 0; j < 4; j++) {
      int n = n0 + wc * 64 + j * 16 + l16;
      float bv = bias ? bias[n] : 0.f;
      if (MODE == 1) {
        #pragma unroll
        for (int r = 0; r < 4; r++)
          ((float*)Out)[(size_t)(mbase + r) * N + n] = acc[i][j][r] + bv;
      } else if (blockIdx.z == 2) {
        // V: write transposed Vt[((b*16+h)*64+dd)*2048 + s], 4 consecutive s packed
        int bb = mbase >> 11, ss = mbase & 2047;
        int hh = n >> 6, dd = n & 63;
        unsigned short pk[4];
        #pragma unroll
        for (int r = 0; r < 4; r++) pk[r] = f2bf(acc[i][j][r] + bv);
        *(unsigned long long*)((unsigned short*)Out +
            (((size_t)(bb * H_ + hh) * D_ + dd) * S_ + ss)) = *(unsigned long long*)pk;
      } else if (j < 2) {
        // rope columns: head-dim index jh = j*16 + l16 < 32 (wave-uniform branch)
        int jh = j * 16 + l16;
        #pragma unroll
        for (int r = 0; r < 4; r++) {
          int row = mbase + r, bb = row >> 11, ss = row & 2047;
          float sn = sins[((size_t)(bb * 2 + 0) * S_ + ss) * ROT_ + jh];
          float cs = sins[((size_t)(bb * 2 + 1) * S_ + ss) * ROT_ + jh];
          float f = (jh & 1) ? (cs + sn) : (cs - sn);
          ((unsigned short*)Out)[(size_t)row * N + n] = f2bf((acc[i][j][r] + bv) * f * sc);
        }
      } else {
        #pragma unroll
        for (int r = 0; r < 4; r++)
          ((unsigned short*)Out)[(size_t)(mbase + r) * N + n] = f2bf((acc[i][j][r] + bv) * sc);
      }
    }
  }
}

// ---- final projection GEMM: 128(M)x64(N) tile, fp32 out, 2-phase pipeline ----
__global__ __launch_bounds__(256) void gemm_bt64(
    const unsigned short* __restrict__ A, const unsigned short* __restrict__ Bt,
    float* __restrict__ Out)
{
  const int K = HID_, N = HID_;
  int m0 = blockIdx.y * 128, n0 = blockIdx.x * 64;
  __shared__ alignas(16) unsigned short sA[2][128 * 32];
  __shared__ alignas(16) unsigned short sB[2][64 * 32];
  int t = threadIdx.x;
  int lane = t & 63, wave = t >> 6;
  int quad = lane >> 4, l16 = lane & 15;
  int wr = wave >> 1, wc = wave & 1;   // per-wave 64(M) x 32(N)

  int srow = lane >> 2, scol = (lane & 3) * 8;
  const unsigned short* gA0 = A  + (size_t)(m0 + wave*32 +  0 + srow) * K + scol;
  const unsigned short* gA1 = A  + (size_t)(m0 + wave*32 + 16 + srow) * K + scol;
  const unsigned short* gB0 = Bt + (size_t)(n0 + wave*16 + srow) * K + scol;

#define GSTAGE(bi, k0) do { \
    gload_lds16(gA0 + (k0), sA[bi] + (wave*32 +  0) * 32); \
    gload_lds16(gA1 + (k0), sA[bi] + (wave*32 + 16) * 32); \
    gload_lds16(gB0 + (k0), sB[bi] + (wave*16) * 32); \
  } while (0)

  floatx4 acc[4][2];
  #pragma unroll
  for (int i = 0; i < 4; i++)
    #pragma unroll
    for (int j = 0; j < 2; j++)
      acc[i][j] = (floatx4){0.f, 0.f, 0.f, 0.f};

  GSTAGE(0, 0);
  __syncthreads();
  for (int ks = 0; ks < K / 32; ks++) {
    int cur = ks & 1;
    if (ks + 1 < K / 32) GSTAGE(cur ^ 1, (ks + 1) * 32);
    short8 af[4], bf[2];
    #pragma unroll
    for (int i = 0; i < 4; i++)
      af[i] = *(const short8*)(sA[cur] + (wr * 64 + i * 16 + l16) * 32 + quad * 8);
    #pragma unroll
    for (int j = 0; j < 2; j++)
      bf[j] = *(const short8*)(sB[cur] + (wc * 32 + j * 16 + l16) * 32 + quad * 8);
    #pragma unroll
    for (int i = 0; i < 4; i++)
      #pragma unroll
      for (int j = 0; j < 2; j++)
        acc[i][j] = __builtin_amdgcn_mfma_f32_16x16x32_bf16(af[i], bf[j], acc[i][j], 0, 0, 0);
    __syncthreads();
  }
#undef GSTAGE

  #pragma unroll
  for (int i = 0; i < 4; i++) {
    int mbase = m0 + wr * 64 + i * 16 + quad * 4;
    #pragma unroll
    for (int j = 0; j < 2; j++) {
      int n = n0 + wc * 32 + j * 16 + l16;
      #pragma unroll
      for (int r = 0; r < 4; r++)
        Out[(size_t)(mbase + r) * N + n] = acc[i][j][r];
    }
  }
}

// ---------------- flash attention (FROZEN at R5 best: 97.8us) ----------------
// R6 lesson: PV-as-32x32x16 via shfl_xor serialized the softmax->PV chain
// (MfmaUtil 20.6 -> 10.9, +25us). Reverted verbatim to the R5 kernel. attn is
// latency-floored at ~98us across occupancy 18-43% and 5 structural variants;
// pivoting effort to the ~176us GEMM side.
__global__ __launch_bounds__(512, 1) void attn(
    const unsigned short* __restrict__ Q, const unsigned short* __restrict__ Kb,
    const unsigned short* __restrict__ Vt, const float* __restrict__ bias,
    unsigned short* __restrict__ Out)
{
  int b = blockIdx.z, h = blockIdx.y;
  int t = threadIdx.x;
  int lane = t & 63, wave = t >> 6;
  int g = wave >> 2, wg = wave & 3;
  int l32 = lane & 31, hl = lane >> 5;
  int s7 = l32 & 7;
  int q0 = blockIdx.x * 128 + wg * 32;
  const int RS = H_ * D_;
  const int NT = S_ / 128;   // 16 tiles of 64 keys per k-half

  // LDS (shorts), per group 32768: K buf[i] at i*4096, V buf[i] at 16384+i*4096
  __shared__ alignas(16) unsigned short smem[65536];   // 128 KB
  unsigned short* bg = smem + g * 32768;

  const unsigned short* Qbase = Q + ((size_t)(b * S_) * H_ + h) * D_;
  const unsigned short* Kbase = Kb + ((size_t)(b * S_) * H_ + h) * D_;
  const unsigned short* Vbase = Vt + ((size_t)(b * H_) + h) * D_ * S_;

  // Q B-frags (n=q=lane&31, k=d=16s+8hl+j), fixed for whole kernel
  short8 qf[4];
  {
    const unsigned short* qp = Qbase + (size_t)(q0 + l32) * RS + 8 * hl;
    qf[0] = *(const short8*)(qp);
    qf[1] = *(const short8*)(qp + 16);
    qf[2] = *(const short8*)(qp + 32);
    qf[3] = *(const short8*)(qp + 48);
  }

  // staging geometry: group-local thread tg covers 16B chunk d=tg (rows 0..31)
  // and d=256+tg (rows 32..63); 8 chunks per 128B row; source chunk pre-swizzled.
  int tg = t & 255;
  int row0 = tg >> 3;                  // 0..31
  int csw  = (tg & 7) ^ (row0 & 7);    // swizzled source chunk (row&7 same for row0+32)
  const unsigned short* gK0 = Kbase + (size_t)(g*1024 + row0)      * RS + csw * 8;
  const unsigned short* gK1 = Kbase + (size_t)(g*1024 + row0 + 32) * RS + csw * 8;
  const unsigned short* gV0 = Vbase + (size_t)(row0)      * S_ + g*1024 + csw * 8;
  const unsigned short* gV1 = Vbase + (size_t)(row0 + 32) * S_ + g*1024 + csw * 8;

  const float* bp = bias + (size_t)b * S_ * S_ + (size_t)(q0 + l32) * S_ + g * 1024 + 4 * hl;

#define STAGE(bi, tk) do { \
    unsigned short* kb_ = bg + (bi) * 4096; \
    unsigned short* vb_ = bg + 16384 + (bi) * 4096; \
    size_t ko_ = (size_t)(tk) * 64 * RS; int vo_ = (tk) * 64; \
    gload_lds16(gK0 + ko_, kb_ + tg * 8); \
    gload_lds16(gK1 + ko_, kb_ + (256 + tg) * 8); \
    gload_lds16(gV0 + vo_, vb_ + tg * 8); \
    gload_lds16(gV1 + vo_, vb_ + (256 + tg) * 8); \
  } while (0)

  float l_run = 0.f;
  floatx16 o0, o1;
  #pragma unroll
  for (int r = 0; r < 16; r++) { o0[r] = 0.f; o1[r] = 0.f; }

  // prologue (VMEM order matters for the counted waits):
  // stage(0) 4, bias(0) 8, stage(1) 4, stage(2) 4  -> 20 in flight
  STAGE(0, 0);
  floatx4 b0[4], b1[4];
  #pragma unroll
  for (int rg = 0; rg < 4; rg++) {
    b0[rg] = *(const floatx4*)(bp + 8 * rg);
    b1[rg] = *(const floatx4*)(bp + 32 + 8 * rg);
  }
  STAGE(1, 1);
  STAGE(2, 2);

  for (int it = 0; it < NT; ++it) {
    int cur = it & 3;
    // counted wait: stage(cur) complete, newer stages + bias stay in flight
    asm volatile("s_waitcnt vmcnt(16)" ::: "memory");
    __builtin_amdgcn_s_barrier();
    __builtin_amdgcn_sched_barrier(0);
    if (it < NT - 3) STAGE((it + 3) & 3, it + 3);

    const unsigned short* kbuf = bg + cur * 4096;
    const unsigned short* vbuf = bg + 16384 + cur * 4096;
    int itn = ((it + 1) & (NT - 1)) * 64;

    // ---- QK^T half 0: S^T rows k=0..31 (D[m=k][n=q]) ----
    floatx16 st;
    #pragma unroll
    for (int r = 0; r < 16; r++) st[r] = 0.f;
    __builtin_amdgcn_s_setprio(1);
    #pragma unroll
    for (int ks = 0; ks < 4; ks++) {
      short8 kf = *(const short8*)(kbuf + l32 * 64 + (((2 * ks + hl) ^ s7) * 8));
      st = __builtin_amdgcn_mfma_f32_32x32x16_bf16(kf, qf[ks], st, 0, 0, 0);
    }
    __builtin_amdgcn_s_setprio(0);

    // ---- softmax half 0 -> pf0; refill b0 for next tile ----
    short4v pf0[4];
    #pragma unroll
    for (int rg = 0; rg < 4; rg++) {
      float p0 = __builtin_amdgcn_exp2f(st[rg * 4 + 0]);
      float p1 = __builtin_amdgcn_exp2f(st[rg * 4 + 1]);
      float p2 = __builtin_amdgcn_exp2f(st[rg * 4 + 2]);
      float p3 = __builtin_amdgcn_exp2f(st[rg * 4 + 3]);
      l_run += (p0 + p1) + (p2 + p3);
      uint2v u;
      u[0] = cvt_pk_bf16(p0 * b0[rg][0], p1 * b0[rg][1]);
      u[1] = cvt_pk_bf16(p2 * b0[rg][2], p3 * b0[rg][3]);
      pf0[rg] = __builtin_bit_cast(short4v, u);
    }
    #pragma unroll
    for (int rg = 0; rg < 4; rg++)
      b0[rg] = *(const floatx4*)(bp + itn + 8 * rg);

    // ---- QK^T half 1 (st registers recycled) ----
    floatx16 st1;
    #pragma unroll
    for (int r = 0; r < 16; r++) st1[r] = 0.f;
    __builtin_amdgcn_s_setprio(1);
    #pragma unroll
    for (int ks = 0; ks < 4; ks++) {
      short8 kf = *(const short8*)(kbuf + (32 + l32) * 64 + (((2 * ks + hl) ^ s7) * 8));
      st1 = __builtin_amdgcn_mfma_f32_32x32x16_bf16(kf, qf[ks], st1, 0, 0, 0);
    }
    // ---- PV half 0 ----
    #pragma unroll
    for (int gg = 0; gg < 4; gg++) {
      int ch = (gg ^ s7) * 8 + hl * 4;
      short4v vf0 = *(const short4v*)(vbuf + l32 * 64 + ch);
      short4v vf1 = *(const short4v*)(vbuf + (32 + l32) * 64 + ch);
      o0 = __builtin_amdgcn_mfma_f32_32x32x8bf16_1k(pf0[gg], vf0, o0, 0, 0, 0);
      o1 = __builtin_amdgcn_mfma_f32_32x32x8bf16_1k(pf0[gg], vf1, o1, 0, 0, 0);
    }
    __builtin_amdgcn_s_setprio(0);

    // ---- softmax half 1 -> pf1; refill b1 ----
    short4v pf1[4];
    #pragma unroll
    for (int rg = 0; rg < 4; rg++) {
      float p0 = __builtin_amdgcn_exp2f(st1[rg * 4 + 0]);
      float p1 = __builtin_amdgcn_exp2f(st1[rg * 4 + 1]);
      float p2 = __builtin_amdgcn_exp2f(st1[rg * 4 + 2]);
      float p3 = __builtin_amdgcn_exp2f(st1[rg * 4 + 3]);
      l_run += (p0 + p1) + (p2 + p3);
      uint2v u;
      u[0] = cvt_pk_bf16(p0 * b1[rg][0], p1 * b1[rg][1]);
      u[1] = cvt_pk_bf16(p2 * b1[rg][2], p3 * b1[rg][3]);
      pf1[rg] = __builtin_bit_cast(short4v, u);
    }
    #pragma unroll
    for (int rg = 0; rg < 4; rg++)
      b1[rg] = *(const floatx4*)(bp + itn + 32 + 8 * rg);

    // ---- PV half 1 ----
    __builtin_amdgcn_s_setprio(1);
    #pragma unroll
    for (int gg = 0; gg < 4; gg++) {
      int ch = ((4 + gg) ^ s7) * 8 + hl * 4;
      short4v vf0 = *(const short4v*)(vbuf + l32 * 64 + ch);
      short4v vf1 = *(const short4v*)(vbuf + (32 + l32) * 64 + ch);
      o0 = __builtin_amdgcn_mfma_f32_32x32x8bf16_1k(pf1[gg], vf0, o0, 0, 0, 0);
      o1 = __builtin_amdgcn_mfma_f32_32x32x8bf16_1k(pf1[gg], vf1, o1, 0, 0, 0);
    }
    __builtin_amdgcn_s_setprio(0);
  }
#undef STAGE

  // full k-half denominator for q-row l32 (partner half-lane has the other half)
  float l2 = l_run + __shfl_xor(l_run, 32);

  // combine the two k-halves through LDS (K/V buffers dead after the loop)
  float* sO = (float*)smem;              // 128 q x 64 d fp32 = 32 KB
  float* sL = (float*)(smem + 16384);    // 128 floats

  __syncthreads();
  if (g == 1) {
    #pragma unroll
    for (int r = 0; r < 16; r++) {
      int ql = (r & 3) + 8 * (r >> 2) + 4 * hl;
      sO[(wg * 32 + ql) * 64 + l32]      = o0[r];
      sO[(wg * 32 + ql) * 64 + 32 + l32] = o1[r];
    }
    if (hl == 0) sL[wg * 32 + l32] = l2;
  }
  __syncthreads();
  if (g == 0) {
    float linv = __builtin_amdgcn_rcpf(l2 + sL[wg * 32 + l32]);
    #pragma unroll
    for (int r = 0; r < 16; r++) {
      int ql = (r & 3) + 8 * (r >> 2) + 4 * hl;
      float sc = __shfl(linv, ql);
      size_t base = ((size_t)(b * S_ + q0 + ql) * H_ + h) * D_;
      float a0 = o0[r] + sO[(wg * 32 + ql) * 64 + l32];
      float a1 = o1[r] + sO[(wg * 32 + ql) * 64 + 32 + l32];
      Out[base + l32]      = f2bf(a0 * sc);
      Out[base + 32 + l32] = f2bf(a1 * sc);
    }
  }
}

// ---------------- launch ----------------
extern "C" void kernel_launch(void* const* d_in, const int* in_sizes, int n_in,
                              void* d_out, int out_size, void* d_ws, size_t ws_size,
                              hipStream_t stream) {
  (void)in_sizes; (void)n_in; (void)out_size; (void)ws_size;
  const float* x    = (const float*)d_in[0];
  const float* sins = (const float*)d_in[1];
  const float* ab   = (const float*)d_in[2];
  const float* Wq   = (const float*)d_in[3];
  const float* bq   = (const float*)d_in[4];
  const float* Wk   = (const float*)d_in[5];
  const float* bk   = (const float*)d_in[6];
  const float* Wv   = (const float*)d_in[7];
  const float* bv   = (const float*)d_in[8];
  const float* Wo   = (const float*)d_in[9];
  float* out = (float*)d_out;
  char* ws = (char*)d_ws;

  unsigned short* xb  = (unsigned short*)(ws);                       // 8 MB
  unsigned short* Wqt = (unsigned short*)(ws + ((size_t) 8 << 20));  // 2 MB each
  unsigned short* Wkt = (unsigned short*)(ws + ((size_t)10 << 20));
  unsigned short* Wvt = (unsigned short*)(ws + ((size_t)12 << 20));
  unsigned short* Wot = (unsigned short*)(ws + ((size_t)14 << 20));
  unsigned short* Qb  = (unsigned short*)(ws + ((size_t)16 << 20));  // 8 MB
  unsigned short* Kb  = (unsigned short*)(ws + ((size_t)24 << 20));  // 8 MB
  unsigned short* Vtb = (unsigned short*)(ws + ((size_t)32 << 20));  // 8 MB, [b][h][d][s]
  unsigned short* Ab  = (unsigned short*)(ws + ((size_t)40 << 20));  // 8 MB

  const float c1 = 0.125f * 1.44269504088896f;  // 1/sqrt(D) * log2(e), folded into Q

  cast_bf16<<<dim3((M_ * HID_) / (256 * 4)), dim3(256), 0, stream>>>(x, xb);
  transW<<<dim3(32, 32, 4), dim3(32, 8), 0, stream>>>(Wq, Wk, Wv, Wo, Wqt, Wkt, Wvt, Wot);
  gemm_bt<0><<<dim3(8, 32, 3), dim3(256), 0, stream>>>(xb, Wqt, Wkt, Wvt, bq, bk, bv,
                                                       Qb, Kb, Vtb, sins, c1);
  attn<<<dim3(S_ / 128, H_, B_), dim3(512), 0, stream>>>(Qb, Kb, Vtb, ab, Ab);
  gemm_bt64<<<dim3(HID_ / 64, M_ / 128), dim3(256), 0, stream>>>(Ab, Wot, out);
}

// Round 8
// 258.611 us; speedup vs baseline: 1.1530x; 1.0128x over previous
//
#include <hip/hip_runtime.h>
#include <math.h>

#define B_   2
#define S_   2048
#define HID_ 1024
#define D_   64
#define H_   16
#define ROT_ 32
#define M_   (B_*S_)

typedef __attribute__((ext_vector_type(4))) short  short4v;
typedef __attribute__((ext_vector_type(8))) short  short8;
typedef __attribute__((ext_vector_type(4))) float  floatx4;
typedef __attribute__((ext_vector_type(16))) float floatx16;
typedef __attribute__((ext_vector_type(2))) unsigned int uint2v;

__device__ __forceinline__ unsigned short f2bf(float f) {
  unsigned int x = __builtin_bit_cast(unsigned int, f);
  x += 0x7fffu + ((x >> 16) & 1u);   // RNE; inputs finite
  return (unsigned short)(x >> 16);
}
__device__ __forceinline__ unsigned int cvt_pk_bf16(float lo, float hi) {
  unsigned int r;
  asm("v_cvt_pk_bf16_f32 %0, %1, %2" : "=v"(r) : "v"(lo), "v"(hi));
  return r;
}
// async global->LDS, 16B per lane; lds dest = wave-uniform base + lane*16
__device__ __forceinline__ void gload_lds16(const unsigned short* g, unsigned short* l) {
  __builtin_amdgcn_global_load_lds(
      (const __attribute__((address_space(1))) unsigned int*)g,
      (__attribute__((address_space(3))) unsigned int*)l, 16, 0, 0);
}

// ---------------- cast x (fp32 -> bf16) ----------------
__global__ void cast_bf16(const float* __restrict__ in, unsigned short* __restrict__ out) {
  int i = (blockIdx.x * 256 + threadIdx.x) * 4;
  floatx4 v = *(const floatx4*)(in + i);
  unsigned short o[4];
  o[0] = f2bf(v[0]); o[1] = f2bf(v[1]); o[2] = f2bf(v[2]); o[3] = f2bf(v[3]);
  *(unsigned long long*)(out + i) = *(unsigned long long*)o;
}

// ------------- transpose + cast weights: T[n][k] = bf16(W[k][n]) -------------
__global__ void transW(const float* __restrict__ W0, const float* __restrict__ W1,
                       const float* __restrict__ W2, const float* __restrict__ W3,
                       unsigned short* __restrict__ T0, unsigned short* __restrict__ T1,
                       unsigned short* __restrict__ T2, unsigned short* __restrict__ T3) {
  const float* W; unsigned short* T;
  int z = blockIdx.z;
  if (z == 0)      { W = W0; T = T0; }
  else if (z == 1) { W = W1; T = T1; }
  else if (z == 2) { W = W2; T = T2; }
  else             { W = W3; T = T3; }
  __shared__ float tile[32][33];
  int bx = blockIdx.x * 32, by = blockIdx.y * 32;
  int tx = threadIdx.x, ty = threadIdx.y;
  #pragma unroll
  for (int j = 0; j < 4; j++)
    tile[ty + j*8][tx] = W[(size_t)(by + ty + j*8) * HID_ + bx + tx];
  __syncthreads();
  #pragma unroll
  for (int j = 0; j < 4; j++)
    T[(size_t)(bx + ty + j*8) * HID_ + by + tx] = f2bf(tile[tx][ty + j*8]);
}

// ---------------- GEMM: C[M,N] = A[M,K] @ Bt[N,K]^T (+bias) ----------------
// R8 (T4): 3-buffer LDS, ONE raw s_barrier per K-step, counted vmcnt(4)
// (vmcnt(0) only at the last step). R7's 2-phase still drained vmcnt(0) at
// its second barrier every step; now stage(t+1..t+2) stay in flight across
// the barrier. Safety: stage(t+2)->buf (t+2)%3 is distinct from the two live
// buffers; readers of the overwritten buffer are proven done by the top-of-
// step barrier (their lgkmcnt drained before the previous step's MFMAs).
// MODE 0: QKV producer. z=0: Q bf16, rope + scale c1. z=1: K bf16, rope.
//         z=2: V bf16 written TRANSPOSED into Vt[b][h][d][s].
template <int MODE>
__global__ __launch_bounds__(256) void gemm_bt(
    const unsigned short* __restrict__ A,
    const unsigned short* __restrict__ Bt0, const unsigned short* __restrict__ Bt1,
    const unsigned short* __restrict__ Bt2,
    const float* __restrict__ bias0, const float* __restrict__ bias1,
    const float* __restrict__ bias2,
    void* __restrict__ out0, void* __restrict__ out1, void* __restrict__ out2,
    const float* __restrict__ sins, float sc0)
{
  const unsigned short* Bt; const float* bias; void* Out; float sc;
  if (blockIdx.z == 0)      { Bt = Bt0; bias = bias0; Out = out0; sc = sc0; }
  else if (blockIdx.z == 1) { Bt = Bt1; bias = bias1; Out = out1; sc = 1.f; }
  else                      { Bt = Bt2; bias = bias2; Out = out2; sc = 1.f; }
  const int K = HID_, N = HID_;
  int m0 = blockIdx.y * 128, n0 = blockIdx.x * 128;
  __shared__ alignas(16) unsigned short sA[3][128 * 32];   // 8 KB x3
  __shared__ alignas(16) unsigned short sB[3][128 * 32];
  int t = threadIdx.x;
  int lane = t & 63, wave = t >> 6;
  int quad = lane >> 4, l16 = lane & 15;
  int wr = wave >> 1, wc = wave & 1;

  int srow = (lane >> 2), scol = (lane & 3) * 8;
  const unsigned short* gA0 = A  + (size_t)(m0 + wave*32 +  0 + srow) * K + scol;
  const unsigned short* gA1 = A  + (size_t)(m0 + wave*32 + 16 + srow) * K + scol;
  const unsigned short* gB0 = Bt + (size_t)(n0 + wave*32 +  0 + srow) * K + scol;
  const unsigned short* gB1 = Bt + (size_t)(n0 + wave*32 + 16 + srow) * K + scol;

#define GSTAGE(bi, k0) do { \
    gload_lds16(gA0 + (k0), sA[bi] + (wave*32 +  0) * 32); \
    gload_lds16(gA1 + (k0), sA[bi] + (wave*32 + 16) * 32); \
    gload_lds16(gB0 + (k0), sB[bi] + (wave*32 +  0) * 32); \
    gload_lds16(gB1 + (k0), sB[bi] + (wave*32 + 16) * 32); \
  } while (0)

  floatx4 acc[4][4];
  #pragma unroll
  for (int i = 0; i < 4; i++)
    #pragma unroll
    for (int j = 0; j < 4; j++)
      acc[i][j] = (floatx4){0.f, 0.f, 0.f, 0.f};

  const int NK = K / 32;                 // 32 steps
  GSTAGE(0, 0);
  GSTAGE(1, 32);
  for (int ks = 0; ks < NK; ks++) {
    int cur = ks % 3;
    // counted wait: stage(ks) complete, stage(ks+1) stays in flight
    if (ks + 1 < NK) asm volatile("s_waitcnt vmcnt(4)" ::: "memory");
    else             asm volatile("s_waitcnt vmcnt(0)" ::: "memory");
    __builtin_amdgcn_s_barrier();
    __builtin_amdgcn_sched_barrier(0);
    if (ks + 2 < NK) GSTAGE((ks + 2) % 3, (ks + 2) * 32);

    short8 af[4], bf[4];
    #pragma unroll
    for (int i = 0; i < 4; i++) {
      af[i] = *(const short8*)(sA[cur] + (wr * 64 + i * 16 + l16) * 32 + quad * 8);
      bf[i] = *(const short8*)(sB[cur] + (wc * 64 + i * 16 + l16) * 32 + quad * 8);
    }
    #pragma unroll
    for (int i = 0; i < 4; i++)
      #pragma unroll
      for (int j = 0; j < 4; j++)
        acc[i][j] = __builtin_amdgcn_mfma_f32_16x16x32_bf16(af[i], bf[j], acc[i][j], 0, 0, 0);
  }
#undef GSTAGE

  // Epilogue. C/D layout: col = lane&15, row = quad*4 + reg.
  #pragma unroll
  for (int i = 0; i < 4; i++) {
    int mbase = m0 + wr * 64 + i * 16 + quad * 4;
    #pragma unroll
    for (int j = 0; j < 4; j++) {
      int n = n0 + wc * 64 + j * 16 + l16;
      float bv = bias ? bias[n] : 0.f;
      if (MODE == 1) {
        #pragma unroll
        for (int r = 0; r < 4; r++)
          ((float*)Out)[(size_t)(mbase + r) * N + n] = acc[i][j][r] + bv;
      } else if (blockIdx.z == 2) {
        // V: write transposed Vt[((b*16+h)*64+dd)*2048 + s], 4 consecutive s packed
        int bb = mbase >> 11, ss = mbase & 2047;
        int hh = n >> 6, dd = n & 63;
        unsigned short pk[4];
        #pragma unroll
        for (int r = 0; r < 4; r++) pk[r] = f2bf(acc[i][j][r] + bv);
        *(unsigned long long*)((unsigned short*)Out +
            (((size_t)(bb * H_ + hh) * D_ + dd) * S_ + ss)) = *(unsigned long long*)pk;
      } else if (j < 2) {
        // rope columns: head-dim index jh = j*16 + l16 < 32 (wave-uniform branch)
        int jh = j * 16 + l16;
        #pragma unroll
        for (int r = 0; r < 4; r++) {
          int row = mbase + r, bb = row >> 11, ss = row & 2047;
          float sn = sins[((size_t)(bb * 2 + 0) * S_ + ss) * ROT_ + jh];
          float cs = sins[((size_t)(bb * 2 + 1) * S_ + ss) * ROT_ + jh];
          float f = (jh & 1) ? (cs + sn) : (cs - sn);
          ((unsigned short*)Out)[(size_t)row * N + n] = f2bf((acc[i][j][r] + bv) * f * sc);
        }
      } else {
        #pragma unroll
        for (int r = 0; r < 4; r++)
          ((unsigned short*)Out)[(size_t)(mbase + r) * N + n] = f2bf((acc[i][j][r] + bv) * sc);
      }
    }
  }
}

// ---- final projection GEMM: 128(M)x64(N) tile, fp32 out, T4 3-buffer ----
__global__ __launch_bounds__(256) void gemm_bt64(
    const unsigned short* __restrict__ A, const unsigned short* __restrict__ Bt,
    float* __restrict__ Out)
{
  const int K = HID_, N = HID_;
  int m0 = blockIdx.y * 128, n0 = blockIdx.x * 64;
  __shared__ alignas(16) unsigned short sA[3][128 * 32];
  __shared__ alignas(16) unsigned short sB[3][64 * 32];
  int t = threadIdx.x;
  int lane = t & 63, wave = t >> 6;
  int quad = lane >> 4, l16 = lane & 15;
  int wr = wave >> 1, wc = wave & 1;   // per-wave 64(M) x 32(N)

  int srow = lane >> 2, scol = (lane & 3) * 8;
  const unsigned short* gA0 = A  + (size_t)(m0 + wave*32 +  0 + srow) * K + scol;
  const unsigned short* gA1 = A  + (size_t)(m0 + wave*32 + 16 + srow) * K + scol;
  const unsigned short* gB0 = Bt + (size_t)(n0 + wave*16 + srow) * K + scol;

#define GSTAGE(bi, k0) do { \
    gload_lds16(gA0 + (k0), sA[bi] + (wave*32 +  0) * 32); \
    gload_lds16(gA1 + (k0), sA[bi] + (wave*32 + 16) * 32); \
    gload_lds16(gB0 + (k0), sB[bi] + (wave*16) * 32); \
  } while (0)

  floatx4 acc[4][2];
  #pragma unroll
  for (int i = 0; i < 4; i++)
    #pragma unroll
    for (int j = 0; j < 2; j++)
      acc[i][j] = (floatx4){0.f, 0.f, 0.f, 0.f};

  const int NK = K / 32;
  GSTAGE(0, 0);
  GSTAGE(1, 32);
  for (int ks = 0; ks < NK; ks++) {
    int cur = ks % 3;
    if (ks + 1 < NK) asm volatile("s_waitcnt vmcnt(3)" ::: "memory");
    else             asm volatile("s_waitcnt vmcnt(0)" ::: "memory");
    __builtin_amdgcn_s_barrier();
    __builtin_amdgcn_sched_barrier(0);
    if (ks + 2 < NK) GSTAGE((ks + 2) % 3, (ks + 2) * 32);

    short8 af[4], bf[2];
    #pragma unroll
    for (int i = 0; i < 4; i++)
      af[i] = *(const short8*)(sA[cur] + (wr * 64 + i * 16 + l16) * 32 + quad * 8);
    #pragma unroll
    for (int j = 0; j < 2; j++)
      bf[j] = *(const short8*)(sB[cur] + (wc * 32 + j * 16 + l16) * 32 + quad * 8);
    #pragma unroll
    for (int i = 0; i < 4; i++)
      #pragma unroll
      for (int j = 0; j < 2; j++)
        acc[i][j] = __builtin_amdgcn_mfma_f32_16x16x32_bf16(af[i], bf[j], acc[i][j], 0, 0, 0);
  }
#undef GSTAGE

  #pragma unroll
  for (int i = 0; i < 4; i++) {
    int mbase = m0 + wr * 64 + i * 16 + quad * 4;
    #pragma unroll
    for (int j = 0; j < 2; j++) {
      int n = n0 + wc * 32 + j * 16 + l16;
      #pragma unroll
      for (int r = 0; r < 4; r++)
        Out[(size_t)(mbase + r) * N + n] = acc[i][j][r];
    }
  }
}

// ---------------- flash attention (FROZEN at R5 best: ~98us) ----------------
// R6 lesson: PV-as-32x32x16 via shfl_xor serialized the softmax->PV chain.
// attn is latency-floored at ~98us across occupancy 18-43% and 5 variants.
__global__ __launch_bounds__(512, 1) void attn(
    const unsigned short* __restrict__ Q, const unsigned short* __restrict__ Kb,
    const unsigned short* __restrict__ Vt, const float* __restrict__ bias,
    unsigned short* __restrict__ Out)
{
  int b = blockIdx.z, h = blockIdx.y;
  int t = threadIdx.x;
  int lane = t & 63, wave = t >> 6;
  int g = wave >> 2, wg = wave & 3;
  int l32 = lane & 31, hl = lane >> 5;
  int s7 = l32 & 7;
  int q0 = blockIdx.x * 128 + wg * 32;
  const int RS = H_ * D_;
  const int NT = S_ / 128;   // 16 tiles of 64 keys per k-half

  // LDS (shorts), per group 32768: K buf[i] at i*4096, V buf[i] at 16384+i*4096
  __shared__ alignas(16) unsigned short smem[65536];   // 128 KB
  unsigned short* bg = smem + g * 32768;

  const unsigned short* Qbase = Q + ((size_t)(b * S_) * H_ + h) * D_;
  const unsigned short* Kbase = Kb + ((size_t)(b * S_) * H_ + h) * D_;
  const unsigned short* Vbase = Vt + ((size_t)(b * H_) + h) * D_ * S_;

  // Q B-frags (n=q=lane&31, k=d=16s+8hl+j), fixed for whole kernel
  short8 qf[4];
  {
    const unsigned short* qp = Qbase + (size_t)(q0 + l32) * RS + 8 * hl;
    qf[0] = *(const short8*)(qp);
    qf[1] = *(const short8*)(qp + 16);
    qf[2] = *(const short8*)(qp + 32);
    qf[3] = *(const short8*)(qp + 48);
  }

  // staging geometry: group-local thread tg covers 16B chunk d=tg (rows 0..31)
  // and d=256+tg (rows 32..63); 8 chunks per 128B row; source chunk pre-swizzled.
  int tg = t & 255;
  int row0 = tg >> 3;                  // 0..31
  int csw  = (tg & 7) ^ (row0 & 7);    // swizzled source chunk (row&7 same for row0+32)
  const unsigned short* gK0 = Kbase + (size_t)(g*1024 + row0)      * RS + csw * 8;
  const unsigned short* gK1 = Kbase + (size_t)(g*1024 + row0 + 32) * RS + csw * 8;
  const unsigned short* gV0 = Vbase + (size_t)(row0)      * S_ + g*1024 + csw * 8;
  const unsigned short* gV1 = Vbase + (size_t)(row0 + 32) * S_ + g*1024 + csw * 8;

  const float* bp = bias + (size_t)b * S_ * S_ + (size_t)(q0 + l32) * S_ + g * 1024 + 4 * hl;

#define STAGE(bi, tk) do { \
    unsigned short* kb_ = bg + (bi) * 4096; \
    unsigned short* vb_ = bg + 16384 + (bi) * 4096; \
    size_t ko_ = (size_t)(tk) * 64 * RS; int vo_ = (tk) * 64; \
    gload_lds16(gK0 + ko_, kb_ + tg * 8); \
    gload_lds16(gK1 + ko_, kb_ + (256 + tg) * 8); \
    gload_lds16(gV0 + vo_, vb_ + tg * 8); \
    gload_lds16(gV1 + vo_, vb_ + (256 + tg) * 8); \
  } while (0)

  float l_run = 0.f;
  floatx16 o0, o1;
  #pragma unroll
  for (int r = 0; r < 16; r++) { o0[r] = 0.f; o1[r] = 0.f; }

  // prologue (VMEM order matters for the counted waits):
  // stage(0) 4, bias(0) 8, stage(1) 4, stage(2) 4  -> 20 in flight
  STAGE(0, 0);
  floatx4 b0[4], b1[4];
  #pragma unroll
  for (int rg = 0; rg < 4; rg++) {
    b0[rg] = *(const floatx4*)(bp + 8 * rg);
    b1[rg] = *(const floatx4*)(bp + 32 + 8 * rg);
  }
  STAGE(1, 1);
  STAGE(2, 2);

  for (int it = 0; it < NT; ++it) {
    int cur = it & 3;
    // counted wait: stage(cur) complete, newer stages + bias stay in flight
    asm volatile("s_waitcnt vmcnt(16)" ::: "memory");
    __builtin_amdgcn_s_barrier();
    __builtin_amdgcn_sched_barrier(0);
    if (it < NT - 3) STAGE((it + 3) & 3, it + 3);

    const unsigned short* kbuf = bg + cur * 4096;
    const unsigned short* vbuf = bg + 16384 + cur * 4096;
    int itn = ((it + 1) & (NT - 1)) * 64;

    // ---- QK^T half 0: S^T rows k=0..31 (D[m=k][n=q]) ----
    floatx16 st;
    #pragma unroll
    for (int r = 0; r < 16; r++) st[r] = 0.f;
    __builtin_amdgcn_s_setprio(1);
    #pragma unroll
    for (int ks = 0; ks < 4; ks++) {
      short8 kf = *(const short8*)(kbuf + l32 * 64 + (((2 * ks + hl) ^ s7) * 8));
      st = __builtin_amdgcn_mfma_f32_32x32x16_bf16(kf, qf[ks], st, 0, 0, 0);
    }
    __builtin_amdgcn_s_setprio(0);

    // ---- softmax half 0 -> pf0; refill b0 for next tile ----
    short4v pf0[4];
    #pragma unroll
    for (int rg = 0; rg < 4; rg++) {
      float p0 = __builtin_amdgcn_exp2f(st[rg * 4 + 0]);
      float p1 = __builtin_amdgcn_exp2f(st[rg * 4 + 1]);
      float p2 = __builtin_amdgcn_exp2f(st[rg * 4 + 2]);
      float p3 = __builtin_amdgcn_exp2f(st[rg * 4 + 3]);
      l_run += (p0 + p1) + (p2 + p3);
      uint2v u;
      u[0] = cvt_pk_bf16(p0 * b0[rg][0], p1 * b0[rg][1]);
      u[1] = cvt_pk_bf16(p2 * b0[rg][2], p3 * b0[rg][3]);
      pf0[rg] = __builtin_bit_cast(short4v, u);
    }
    #pragma unroll
    for (int rg = 0; rg < 4; rg++)
      b0[rg] = *(const floatx4*)(bp + itn + 8 * rg);

    // ---- QK^T half 1 (st registers recycled) ----
    floatx16 st1;
    #pragma unroll
    for (int r = 0; r < 16; r++) st1[r] = 0.f;
    __builtin_amdgcn_s_setprio(1);
    #pragma unroll
    for (int ks = 0; ks < 4; ks++) {
      short8 kf = *(const short8*)(kbuf + (32 + l32) * 64 + (((2 * ks + hl) ^ s7) * 8));
      st1 = __builtin_amdgcn_mfma_f32_32x32x16_bf16(kf, qf[ks], st1, 0, 0, 0);
    }
    // ---- PV half 0 ----
    #pragma unroll
    for (int gg = 0; gg < 4; gg++) {
      int ch = (gg ^ s7) * 8 + hl * 4;
      short4v vf0 = *(const short4v*)(vbuf + l32 * 64 + ch);
      short4v vf1 = *(const short4v*)(vbuf + (32 + l32) * 64 + ch);
      o0 = __builtin_amdgcn_mfma_f32_32x32x8bf16_1k(pf0[gg], vf0, o0, 0, 0, 0);
      o1 = __builtin_amdgcn_mfma_f32_32x32x8bf16_1k(pf0[gg], vf1, o1, 0, 0, 0);
    }
    __builtin_amdgcn_s_setprio(0);

    // ---- softmax half 1 -> pf1; refill b1 ----
    short4v pf1[4];
    #pragma unroll
    for (int rg = 0; rg < 4; rg++) {
      float p0 = __builtin_amdgcn_exp2f(st1[rg * 4 + 0]);
      float p1 = __builtin_amdgcn_exp2f(st1[rg * 4 + 1]);
      float p2 = __builtin_amdgcn_exp2f(st1[rg * 4 + 2]);
      float p3 = __builtin_amdgcn_exp2f(st1[rg * 4 + 3]);
      l_run += (p0 + p1) + (p2 + p3);
      uint2v u;
      u[0] = cvt_pk_bf16(p0 * b1[rg][0], p1 * b1[rg][1]);
      u[1] = cvt_pk_bf16(p2 * b1[rg][2], p3 * b1[rg][3]);
      pf1[rg] = __builtin_bit_cast(short4v, u);
    }
    #pragma unroll
    for (int rg = 0; rg < 4; rg++)
      b1[rg] = *(const floatx4*)(bp + itn + 32 + 8 * rg);

    // ---- PV half 1 ----
    __builtin_amdgcn_s_setprio(1);
    #pragma unroll
    for (int gg = 0; gg < 4; gg++) {
      int ch = ((4 + gg) ^ s7) * 8 + hl * 4;
      short4v vf0 = *(const short4v*)(vbuf + l32 * 64 + ch);
      short4v vf1 = *(const short4v*)(vbuf + (32 + l32) * 64 + ch);
      o0 = __builtin_amdgcn_mfma_f32_32x32x8bf16_1k(pf1[gg], vf0, o0, 0, 0, 0);
      o1 = __builtin_amdgcn_mfma_f32_32x32x8bf16_1k(pf1[gg], vf1, o1, 0, 0, 0);
    }
    __builtin_amdgcn_s_setprio(0);
  }
#undef STAGE

  // full k-half denominator for q-row l32 (partner half-lane has the other half)
  float l2 = l_run + __shfl_xor(l_run, 32);

  // combine the two k-halves through LDS (K/V buffers dead after the loop)
  float* sO = (float*)smem;              // 128 q x 64 d fp32 = 32 KB
  float* sL = (float*)(smem + 16384);    // 128 floats

  __syncthreads();
  if (g == 1) {
    #pragma unroll
    for (int r = 0; r < 16; r++) {
      int ql = (r & 3) + 8 * (r >> 2) + 4 * hl;
      sO[(wg * 32 + ql) * 64 + l32]      = o0[r];
      sO[(wg * 32 + ql) * 64 + 32 + l32] = o1[r];
    }
    if (hl == 0) sL[wg * 32 + l32] = l2;
  }
  __syncthreads();
  if (g == 0) {
    float linv = __builtin_amdgcn_rcpf(l2 + sL[wg * 32 + l32]);
    #pragma unroll
    for (int r = 0; r < 16; r++) {
      int ql = (r & 3) + 8 * (r >> 2) + 4 * hl;
      float sc = __shfl(linv, ql);
      size_t base = ((size_t)(b * S_ + q0 + ql) * H_ + h) * D_;
      float a0 = o0[r] + sO[(wg * 32 + ql) * 64 + l32];
      float a1 = o1[r] + sO[(wg * 32 + ql) * 64 + 32 + l32];
      Out[base + l32]      = f2bf(a0 * sc);
      Out[base + 32 + l32] = f2bf(a1 * sc);
    }
  }
}

// ---------------- launch ----------------
extern "C" void kernel_launch(void* const* d_in, const int* in_sizes, int n_in,
                              void* d_out, int out_size, void* d_ws, size_t ws_size,
                              hipStream_t stream) {
  (void)in_sizes; (void)n_in; (void)out_size; (void)ws_size;
  const float* x    = (const float*)d_in[0];
  const float* sins = (const float*)d_in[1];
  const float* ab   = (const float*)d_in[2];
  const float* Wq   = (const float*)d_in[3];
  const float* bq   = (const float*)d_in[4];
  const float* Wk   = (const float*)d_in[5];
  const float* bk   = (const float*)d_in[6];
  const float* Wv   = (const float*)d_in[7];
  const float* bv   = (const float*)d_in[8];
  const float* Wo   = (const float*)d_in[9];
  float* out = (float*)d_out;
  char* ws = (char*)d_ws;

  unsigned short* xb  = (unsigned short*)(ws);                       // 8 MB
  unsigned short* Wqt = (unsigned short*)(ws + ((size_t) 8 << 20));  // 2 MB each
  unsigned short* Wkt = (unsigned short*)(ws + ((size_t)10 << 20));
  unsigned short* Wvt = (unsigned short*)(ws + ((size_t)12 << 20));
  unsigned short* Wot = (unsigned short*)(ws + ((size_t)14 << 20));
  unsigned short* Qb  = (unsigned short*)(ws + ((size_t)16 << 20));  // 8 MB
  unsigned short* Kb  = (unsigned short*)(ws + ((size_t)24 << 20));  // 8 MB
  unsigned short* Vtb = (unsigned short*)(ws + ((size_t)32 << 20));  // 8 MB, [b][h][d][s]
  unsigned short* Ab  = (unsigned short*)(ws + ((size_t)40 << 20));  // 8 MB

  const float c1 = 0.125f * 1.44269504088896f;  // 1/sqrt(D) * log2(e), folded into Q

  cast_bf16<<<dim3((M_ * HID_) / (256 * 4)), dim3(256), 0, stream>>>(x, xb);
  transW<<<dim3(32, 32, 4), dim3(32, 8), 0, stream>>>(Wq, Wk, Wv, Wo, Wqt, Wkt, Wvt, Wot);
  gemm_bt<0><<<dim3(8, 32, 3), dim3(256), 0, stream>>>(xb, Wqt, Wkt, Wvt, bq, bk, bv,
                                                       Qb, Kb, Vtb, sins, c1);
  attn<<<dim3(S_ / 128, H_, B_), dim3(512), 0, stream>>>(Qb, Kb, Vtb, ab, Ab);
  gemm_bt64<<<dim3(HID_ / 64, M_ / 128), dim3(256), 0, stream>>>(Ab, Wot, out);
}